// Round 3
// baseline (294.994 us; speedup 1.0000x reference)
//
#include <hip/hip_runtime.h>
#include <stdint.h>
#include <math.h>

#define B_DIM 32
#define T_DIM 1024
#define C_DIM 768
#define NTILE 8                 // T_DIM / 128
#define NTRI  36                // NTILE*(NTILE+1)/2
#define KITER (C_DIM / 32)      // 24

typedef float f32x4 __attribute__((ext_vector_type(4)));
typedef int   i32x4 __attribute__((ext_vector_type(4)));

// Single fused kernel, ZERO workspace use:
//   out[b,i,j] = 1 - <Q(x_i),Q(x_j)>_fp8 * rs_i * rs_j,   rs = 1/||x||_2 (exact f32)
// e4m3 relative error is scale-invariant, so quantizing RAW x and scaling by the
// exact f32 norms in the epilogue is numerically equivalent to quantizing the
// normalized rows (previous verified version, absmax 0.0140).
//
// Staging: thread t reg-stages 16 f32 of A-panel + 16 of B-panel per K-slice
// (row r = t>>1, half h = t&1), converts to fp8 (cvt_pk), ds_write_b128 into a
// double-buffered [128][32] fp8 tile. Squared-sums accumulate on the staged
// registers across all 24 slices -> rs for free (no separate normalize pass).
// x re-reads are L2-served: batch panel = 3 MB, and the batch-fastest grid puts
// all 36 tiles of a batch on one XCD concurrently (1152 blocks all resident).
//
// LDS half-swizzle (16B granule): row r's half h stored at h ^ ((r>>2)&1);
// applied on BOTH ds_write and ds_read addresses (both-sides rule). Breaks the
// 4-lane bank aliasing of the stride-32B ds_read_b64 fragment reads to 2-way.
__global__ __launch_bounds__(256) void fused_cosdist_fp8(const float* __restrict__ x,
                                                         float* __restrict__ out) {
    __shared__ uint8_t As[2][128 * 32];   // 4 KB per buffer
    __shared__ uint8_t Bs[2][128 * 32];
    __shared__ float rsA[128];
    __shared__ float rsB[128];

    const int b   = blockIdx.x & 31;   // batch fastest -> batch pinned to XCD (b&7)
    const int idx = blockIdx.x >> 5;   // triangular tile index, 0..35
    int tj = (int)((sqrtf(8.0f * (float)idx + 1.0f) - 1.0f) * 0.5f);
    if (tj * (tj + 1) / 2 > idx) --tj;
    const int ti = idx - tj * (tj + 1) / 2;   // ti <= tj

    const int tid  = threadIdx.x;
    const int lane = tid & 63;
    const int wave = tid >> 6;
    const int quad = lane >> 4;
    const int l16  = lane & 15;
    const int wi = wave >> 1;
    const int wj = wave & 1;

    // Staging mapping: thread t -> (row r = t>>1, half h = t&1), 16 f32 each.
    const int r = tid >> 1;
    const int h = tid & 1;
    const float* xb = x + (size_t)b * T_DIM * C_DIM;
    const float* gA = xb + (size_t)(ti * 128 + r) * C_DIM + h * 16;
    const float* gB = xb + (size_t)(tj * 128 + r) * C_DIM + h * 16;
    // Swizzled LDS write byte offset (16B granule XOR on row bit 2).
    const int wbyte = r * 32 + ((h * 16) ^ (((r >> 2) & 1) << 4));

    // Swizzled ds_read fragment offsets: row = w*64+ii*16+l16, slot = quad*8.
    const int sw = ((l16 >> 2) & 1) << 4;
    int offA[4], offB[4];
    #pragma unroll
    for (int ii = 0; ii < 4; ++ii) {
        offA[ii] = (wi * 64 + ii * 16 + l16) * 32 + ((quad * 8) ^ sw);
        offB[ii] = (wj * 64 + ii * 16 + l16) * 32 + ((quad * 8) ^ sw);
    }

    f32x4 acc[4][4];
    #pragma unroll
    for (int i = 0; i < 4; ++i)
        #pragma unroll
        for (int j = 0; j < 4; ++j)
            acc[i][j] = (f32x4){0.f, 0.f, 0.f, 0.f};

    float ssA = 0.f, ssB = 0.f;

#define SS4(v) ((v).x*(v).x + (v).y*(v).y + (v).z*(v).z + (v).w*(v).w)
#define CVT4(v) ({ int _t = __builtin_amdgcn_cvt_pk_fp8_f32((v).x, (v).y, 0, false); \
                   __builtin_amdgcn_cvt_pk_fp8_f32((v).z, (v).w, _t, true); })

    // Prologue: stage K-slice 0 into buffer 0.
    {
        const float4* pA = (const float4*)gA;
        const float4* pB = (const float4*)gB;
        float4 a0 = pA[0], a1 = pA[1], a2 = pA[2], a3 = pA[3];
        float4 b0 = pB[0], b1 = pB[1], b2 = pB[2], b3 = pB[3];
        ssA += SS4(a0) + SS4(a1) + SS4(a2) + SS4(a3);
        ssB += SS4(b0) + SS4(b1) + SS4(b2) + SS4(b3);
        *(i32x4*)&As[0][wbyte] = (i32x4){CVT4(a0), CVT4(a1), CVT4(a2), CVT4(a3)};
        *(i32x4*)&Bs[0][wbyte] = (i32x4){CVT4(b0), CVT4(b1), CVT4(b2), CVT4(b3)};
    }
    __syncthreads();

    for (int it = 0; it < KITER; ++it) {
        const int cur = it & 1;
        const bool more = (it + 1 < KITER);

        // Issue next slice's global loads early (reg-staged; the MFMA phase
        // below covers their L2 latency; compiler inserts counted vmcnt).
        float4 na0, na1, na2, na3, nb0, nb1, nb2, nb3;
        if (more) {
            const float4* pA = (const float4*)(gA + (it + 1) * 32);
            const float4* pB = (const float4*)(gB + (it + 1) * 32);
            na0 = pA[0]; na1 = pA[1]; na2 = pA[2]; na3 = pA[3];
            nb0 = pB[0]; nb1 = pB[1]; nb2 = pB[2]; nb3 = pB[3];
        }

        // Compute on buf[cur].
        long af[4], bfr[4];
        #pragma unroll
        for (int ii = 0; ii < 4; ++ii) {
            af[ii]  = *(const long*)(&As[cur][0] + offA[ii]);
            bfr[ii] = *(const long*)(&Bs[cur][0] + offB[ii]);
        }
        #pragma unroll
        for (int ii = 0; ii < 4; ++ii)
            #pragma unroll
            for (int jj = 0; jj < 4; ++jj)
                acc[ii][jj] = __builtin_amdgcn_mfma_f32_16x16x32_fp8_fp8(af[ii], bfr[jj], acc[ii][jj], 0, 0, 0);

        // Norm accumulation + fp8 conversion + LDS write of next slice.
        // Writes buf[cur^1], which all waves finished reading at iter it-1
        // (guarded by the barrier below).
        if (more) {
            ssA += SS4(na0) + SS4(na1) + SS4(na2) + SS4(na3);
            ssB += SS4(nb0) + SS4(nb1) + SS4(nb2) + SS4(nb3);
            *(i32x4*)&As[cur ^ 1][wbyte] = (i32x4){CVT4(na0), CVT4(na1), CVT4(na2), CVT4(na3)};
            *(i32x4*)&Bs[cur ^ 1][wbyte] = (i32x4){CVT4(nb0), CVT4(nb1), CVT4(nb2), CVT4(nb3)};
        }
        __syncthreads();
    }

    // Finish norms: pair-reduce the two halves of each row, publish rs.
    ssA += __shfl_xor(ssA, 1, 64);
    ssB += __shfl_xor(ssB, 1, 64);
    rsA[r] = rsqrtf(ssA);   // both h-halves write the same value (benign)
    rsB[r] = rsqrtf(ssB);
    __syncthreads();

    // Epilogue. C/D layout: col = lane&15, row = quad*4 + reg.
    // out = 1 - acc * rsA[row] * rsB[col]. Nontemporal stores keep the 134 MB
    // out stream from evicting the L2-hot x panels.
    float* outb = out + (size_t)b * T_DIM * T_DIM;
    #pragma unroll
    for (int ii = 0; ii < 4; ++ii) {
        const int rl = wi * 64 + ii * 16 + quad * 4;       // local row base
        const f32x4 ra = *(const f32x4*)&rsA[rl];
        const int rowbase = ti * 128 + rl;
        #pragma unroll
        for (int jj = 0; jj < 4; ++jj) {
            const int cl  = wj * 64 + jj * 16 + l16;       // local col
            const float rb = rsB[cl];
            const int col = tj * 128 + cl;
            f32x4 v;
            #pragma unroll
            for (int rr = 0; rr < 4; ++rr)
                v[rr] = 1.0f - acc[ii][jj][rr] * (ra[rr] * rb);
            #pragma unroll
            for (int rr = 0; rr < 4; ++rr)
                __builtin_nontemporal_store(v[rr], &outb[(size_t)(rowbase + rr) * T_DIM + col]);
            if (ti != tj) {
                // Mirror tile: one lane's 4 values share a col, 4 consecutive
                // rows -> aligned f32x4 store; 4 quads of same l16 = 64B line.
                __builtin_nontemporal_store(v, (f32x4*)(outb + (size_t)col * T_DIM + rowbase));
            }
        }
    }
#undef SS4
#undef CVT4
}

extern "C" void kernel_launch(void* const* d_in, const int* in_sizes, int n_in,
                              void* d_out, int out_size, void* d_ws, size_t ws_size,
                              hipStream_t stream) {
    const float* x = (const float*)d_in[0];
    float* out = (float*)d_out;
    (void)d_ws; (void)ws_size;   // workspace deliberately unused
    // 1152 blocks, batch-fastest: all 36 tiles of batch b share XCD (b&7).
    fused_cosdist_fp8<<<dim3(NTRI * B_DIM), dim3(256), 0, stream>>>(x, out);
}

// Round 4
// 244.043 us; speedup vs baseline: 1.2088x; 1.2088x over previous
//
#include <hip/hip_runtime.h>
#include <hip/hip_bf16.h>
#include <stdint.h>
#include <math.h>

#define B_DIM 32
#define T_DIM 1024
#define C_DIM 768
#define NTILE 8                 // T_DIM / 128
#define NTRI  36                // NTILE*(NTILE+1)/2
#define KITER (C_DIM / 64)      // 12 iterations of BK=64

typedef float f32x4 __attribute__((ext_vector_type(4)));

typedef __attribute__((address_space(1))) void gvoid_t;
typedef __attribute__((address_space(3))) void lvoid_t;

// One wave per row: compute 1/||x||_2 and store normalized row as fp8 e4m3.
// Row layout: 768 fp8 bytes = 192 dwords; lane L owns dword L, L+64, L+128
// (elements 4L..4L+3 etc.) -> coalesced dword stores.
__global__ __launch_bounds__(256) void normalize_rows_fp8(const float* __restrict__ x,
                                                          uint32_t* __restrict__ m) {
    const int row  = blockIdx.x * 4 + (threadIdx.x >> 6);
    const int lane = threadIdx.x & 63;
    const float4* xr = (const float4*)(x + (size_t)row * C_DIM);
    float4 v0 = xr[lane];
    float4 v1 = xr[lane + 64];
    float4 v2 = xr[lane + 128];
    float ss = v0.x*v0.x + v0.y*v0.y + v0.z*v0.z + v0.w*v0.w
             + v1.x*v1.x + v1.y*v1.y + v1.z*v1.z + v1.w*v1.w
             + v2.x*v2.x + v2.y*v2.y + v2.z*v2.z + v2.w*v2.w;
    #pragma unroll
    for (int off = 32; off > 0; off >>= 1)
        ss += __shfl_xor(ss, off, 64);
    const float rs = rsqrtf(ss);
    uint32_t* mr = m + (size_t)row * (C_DIM / 4);
    int p;
    p = __builtin_amdgcn_cvt_pk_fp8_f32(v0.x * rs, v0.y * rs, 0, false);
    p = __builtin_amdgcn_cvt_pk_fp8_f32(v0.z * rs, v0.w * rs, p, true);
    mr[lane] = (uint32_t)p;
    p = __builtin_amdgcn_cvt_pk_fp8_f32(v1.x * rs, v1.y * rs, 0, false);
    p = __builtin_amdgcn_cvt_pk_fp8_f32(v1.z * rs, v1.w * rs, p, true);
    mr[lane + 64] = (uint32_t)p;
    p = __builtin_amdgcn_cvt_pk_fp8_f32(v2.x * rs, v2.y * rs, 0, false);
    p = __builtin_amdgcn_cvt_pk_fp8_f32(v2.z * rs, v2.w * rs, p, true);
    mr[lane + 128] = (uint32_t)p;
}

// Batched symmetric NT GEMM on fp8 e4m3: out[b,i,j] = 1 - sum_k M[b,i,k]*M[b,j,k].
// Upper-triangular 128x128 tiles only; off-diagonal mirrored via transposed
// f32x4 stores. Batch-fastest flat grid pins each batch's 36 blocks to one XCD.
//
// K-loop: BK=64 (12 iters, HALF the barrier drains of the 250-us BK=32 version).
// Each BK=64 slice is stored as TWO independent [128][32] fp8 sub-blocks, each
// with the proven 16B half-swizzle (row r's half h at h ^ ((r>>2)&1), realized
// by pre-swizzling the GLOBAL source column since global_load_lds writes
// linearly; ds_reads XOR the same bit). 32 MFMA per barrier; fragments loaded
// per sub-slice (8 longs live) to keep the R0 register profile.
// Single-barrier double buffer: stage(next) issued right after the barrier,
// drained by the NEXT barrier's vmcnt(0), overlapping all of compute.
__global__ __launch_bounds__(256) void gemm_nt_sym_fp8(const uint8_t* __restrict__ M,
                                                       float* __restrict__ out) {
    // [buf][ksub][128*32] fp8: 4 KB per sub-block, 16 KB per matrix, 32 KB total.
    __shared__ uint8_t As[2][2][128 * 32];
    __shared__ uint8_t Bs[2][2][128 * 32];

    const int b   = blockIdx.x & 31;   // batch fastest -> batch pinned to XCD (b&7)
    const int idx = blockIdx.x >> 5;   // triangular tile index, 0..35
    int tj = (int)((sqrtf(8.0f * (float)idx + 1.0f) - 1.0f) * 0.5f);
    if (tj * (tj + 1) / 2 > idx) --tj;
    const int ti = idx - tj * (tj + 1) / 2;   // ti <= tj

    const int tid  = threadIdx.x;
    const int wave = tid >> 6;
    const int lane = tid & 63;
    const int quad = lane >> 4;
    const int l16  = lane & 15;
    const int wi = wave >> 1;
    const int wj = wave & 1;

    const uint8_t* Mb = M + (size_t)b * T_DIM * C_DIM;

    // Staging: each sub-block = 4 chunks of 1 KB; wave w stages chunk w.
    // Chunk rows: w*32 .. w*32+31 (32 B/row in the sub-block, 2 lanes per row).
    // LDS dest = wave-uniform chunk base + lane*16 (HW rule); the content
    // permutation is realized by XOR-ing the global source column.
    const int srow = wave * 32 + (lane >> 1);
    const int scol = ((lane & 1) * 16) ^ ((((srow >> 2) & 1)) << 4);

    const uint8_t* gA = Mb + (size_t)(ti * 128 + srow) * C_DIM + scol;
    const uint8_t* gB = Mb + (size_t)(tj * 128 + srow) * C_DIM + scol;
    const int cbase = wave * 1024;

    // Swizzled ds_read fragment offsets within a 4 KB sub-block:
    // row = w*64 + ii*16 + l16, slot = quad*8, sw = ((l16>>2)&1)<<4.
    const int sw = ((l16 >> 2) & 1) << 4;
    int offA[4], offB[4];
    #pragma unroll
    for (int ii = 0; ii < 4; ++ii) {
        offA[ii] = (wi * 64 + ii * 16 + l16) * 32 + ((quad * 8) ^ sw);
        offB[ii] = (wj * 64 + ii * 16 + l16) * 32 + ((quad * 8) ^ sw);
    }

    f32x4 acc[4][4];
    #pragma unroll
    for (int i = 0; i < 4; ++i)
        #pragma unroll
        for (int j = 0; j < 4; ++j)
            acc[i][j] = (f32x4){0.f, 0.f, 0.f, 0.f};

    // Prologue: stage K-slice 0 (both 32B sub-slices) into buffer 0.
    #pragma unroll
    for (int s = 0; s < 2; ++s) {
        __builtin_amdgcn_global_load_lds((gvoid_t*)(gA + s * 32), (lvoid_t*)&As[0][s][cbase], 16, 0, 0);
        __builtin_amdgcn_global_load_lds((gvoid_t*)(gB + s * 32), (lvoid_t*)&Bs[0][s][cbase], 16, 0, 0);
    }

    for (int it = 0; it < KITER; ++it) {
        const int cur = it & 1;
        // Drains this wave's outstanding stage DMA (vmcnt(0) before barrier) and
        // guarantees all waves finished reading buf[cur^1] from iter it-1.
        __syncthreads();
        if (it + 1 < KITER) {
            const int k0 = (it + 1) * 64;   // byte offset along K
            const int nxt = cur ^ 1;
            #pragma unroll
            for (int s = 0; s < 2; ++s) {
                __builtin_amdgcn_global_load_lds((gvoid_t*)(gA + k0 + s * 32), (lvoid_t*)&As[nxt][s][cbase], 16, 0, 0);
                __builtin_amdgcn_global_load_lds((gvoid_t*)(gB + k0 + s * 32), (lvoid_t*)&Bs[nxt][s][cbase], 16, 0, 0);
            }
        }

        // Two sub-slices per barrier: {ds_read x8, 16 MFMA} x2. K-summation
        // order per output element is identical to the BK=32 version.
        #pragma unroll
        for (int s = 0; s < 2; ++s) {
            long af[4], bfr[4];
            #pragma unroll
            for (int ii = 0; ii < 4; ++ii) {
                af[ii]  = *(const long*)&As[cur][s][offA[ii]];
                bfr[ii] = *(const long*)&Bs[cur][s][offB[ii]];
            }
            #pragma unroll
            for (int ii = 0; ii < 4; ++ii)
                #pragma unroll
                for (int jj = 0; jj < 4; ++jj)
                    acc[ii][jj] = __builtin_amdgcn_mfma_f32_16x16x32_fp8_fp8(af[ii], bfr[jj], acc[ii][jj], 0, 0, 0);
        }
    }

    // Epilogue. C/D layout: col = lane&15, row = quad*4 + reg. out = 1 - acc.
    float* outb = out + (size_t)b * T_DIM * T_DIM;
    #pragma unroll
    for (int ii = 0; ii < 4; ++ii) {
        const int rowbase = ti * 128 + wi * 64 + ii * 16 + quad * 4;
        #pragma unroll
        for (int jj = 0; jj < 4; ++jj) {
            const int col = tj * 128 + wj * 64 + jj * 16 + l16;
            #pragma unroll
            for (int r = 0; r < 4; ++r)
                outb[(size_t)(rowbase + r) * T_DIM + col] = 1.0f - acc[ii][jj][r];
        }
    }
    if (ti != tj) {
        // Mirror tile: each lane's 4 acc values share one col and 4 consecutive
        // rows -> one aligned f32x4 store; 4 quads of same l16 cover a 64B line.
        #pragma unroll
        for (int ii = 0; ii < 4; ++ii) {
            const int rowbase = ti * 128 + wi * 64 + ii * 16 + quad * 4;
            #pragma unroll
            for (int jj = 0; jj < 4; ++jj) {
                const int col = tj * 128 + wj * 64 + jj * 16 + l16;
                f32x4 v;
                v[0] = 1.0f - acc[ii][jj][0];
                v[1] = 1.0f - acc[ii][jj][1];
                v[2] = 1.0f - acc[ii][jj][2];
                v[3] = 1.0f - acc[ii][jj][3];
                *(f32x4*)(outb + (size_t)col * T_DIM + rowbase) = v;
            }
        }
    }
}

extern "C" void kernel_launch(void* const* d_in, const int* in_sizes, int n_in,
                              void* d_out, int out_size, void* d_ws, size_t ws_size,
                              hipStream_t stream) {
    const float* x = (const float*)d_in[0];
    float* out = (float*)d_out;
    uint32_t* metric = (uint32_t*)d_ws;  // 32768 x 768 fp8 = 24 MiB

    normalize_rows_fp8<<<dim3((B_DIM * T_DIM) / 4), dim3(256), 0, stream>>>(x, metric);
    // 1152 blocks, batch-fastest: all 36 tiles of batch b share XCD (b&7).
    gemm_nt_sym_fp8<<<dim3(NTRI * B_DIM), dim3(256), 0, stream>>>((const uint8_t*)metric, out);
}